// Round 2
// baseline (623.991 us; speedup 1.0000x reference)
//
#include <hip/hip_runtime.h>

// 9x9 local-max peak detection (threshold 0.5) on 8192x8192 fp32.
//
// Key identity: threshold t(x)=x*[x>0.5] commutes with max (monotone), so
//   conf[r][c] = (M > 0.5 && M == raw[r][c]) ? M : 0,  M = 9x9 raw max.
// 0-padding is equivalent to -inf padding: a pad value can only win the max
// when everything is <= 0, and then the >0.5 gate kills it anyway.
//
// Streaming structure (no LDS, no barriers):
//   wave = 256-col band (lane owns 4 cols via float4), rolls over SR output
//   rows. Per input row: 3 adjacent float4 loads (12 cols: col0-4..col0+7),
//   horizontal 9-max via shared-prefix, 9-deep register ring, vertical
//   9-max, predicate, coalesced NT float4 store. Unroll-by-9 keeps all ring
//   indices compile-time-static (registers, no spills).
//
// Round-2 change — occupancy, not traffic:
//   rocprof showed the kernel latency-bound, not BW-bound: hbm 32% of peak,
//   VALUBusy 22%, Occupancy 39.5% (grid was 1024 blocks = 4/CU = 4 waves/
//   SIMD). Strip halved to SR=32 rows -> 2048 blocks = 8/CU = 32 waves/CU
//   (100% cap; VGPR=44 <= 64, pinned by __launch_bounds__(256,8)). The 25%
//   halo overfetch this costs is mostly L3-absorbed (FETCH_SIZE was already
//   below the input size). Serpentine sweep from round 1 dropped: FETCH
//   evidence shows the LLC already covers halo reuse, and it doubled the
//   unrolled code footprint for nothing.

#define W 8192
#define H 8192
#define THRESH 0.5f
#define SR 32   // output rows per wave-strip

typedef float v4f __attribute__((ext_vector_type(4)));

__device__ __forceinline__ v4f ld4(const float* __restrict__ in, int r, int c) {
    v4f v = {0.f, 0.f, 0.f, 0.f};
    if ((unsigned)c < (unsigned)W) {
        v = *(const v4f*)(in + (size_t)r * W + c);
    }
    return v;
}

__global__ __launch_bounds__(256, 8) void peak_stream(const float* __restrict__ in,
                                                      float* __restrict__ out) {
    const int lane = threadIdx.x;                       // 0..63
    const int col0 = blockIdx.x * 256 + lane * 4;       // this lane's 4 cols
    const int r0   = (blockIdx.y * 4 + threadIdx.y) * SR; // strip's first output row

    v4f hm[9];   // ring: horizontal 9-max of the last 9 input rows
    v4f ce[9];   // ring: raw center values (delayed 4 rows for the compare)

    // One input row: k = ring slot (compile-time const), rin = input row,
    // emit = produce output row rin-4 (center of the 9-row window).
    auto dorow = [&](int rin, int k, bool emit) {
        v4f l = {0.f, 0.f, 0.f, 0.f}, v = l, r = l;
        if ((unsigned)rin < (unsigned)H) {
            l = ld4(in, rin, col0 - 4);
            v = ld4(in, rin, col0);
            r = ld4(in, rin, col0 + 4);
        }
        // L = [l.x l.y l.z l.w v.x v.y v.z v.w r.x r.y r.z r.w]; out j = max L[j..j+8]
        const float common = fmaxf(fmaxf(fmaxf(l.w, v.x), fmaxf(v.y, v.z)),
                                   fmaxf(v.w, r.x));     // max L[3..8]
        const float m12  = fmaxf(l.y, l.z);
        const float m910 = fmaxf(r.y, r.z);
        v4f o;
        o.x = fmaxf(common, fmaxf(l.x, m12));
        o.y = fmaxf(common, fmaxf(m12, r.y));
        o.z = fmaxf(common, fmaxf(l.z, m910));
        o.w = fmaxf(common, fmaxf(m910, r.w));
        hm[k] = o;
        ce[k] = v;
        if (emit) {
            v4f m = hm[0];
#pragma unroll
            for (int j = 1; j < 9; ++j) {
                m.x = fmaxf(m.x, hm[j].x);
                m.y = fmaxf(m.y, hm[j].y);
                m.z = fmaxf(m.z, hm[j].z);
                m.w = fmaxf(m.w, hm[j].w);
            }
            const v4f c4 = ce[(k + 5) % 9];  // raw value at row rin-4
            v4f ov;
            ov.x = (m.x > THRESH && m.x == c4.x) ? m.x : 0.f;
            ov.y = (m.y > THRESH && m.y == c4.y) ? m.y : 0.f;
            ov.z = (m.z > THRESH && m.z == c4.z) ? m.z : 0.f;
            ov.w = (m.w > THRESH && m.w == c4.w) ? m.w : 0.f;
            const int rout = rin - 4;
            __builtin_nontemporal_store(ov, (v4f*)(out + (size_t)rout * W + col0));
        }
    };

    // Prologue: fill the ring (input rows r0-4 .. r0+4); slot 8 emits row r0.
#pragma unroll
    for (int t = 0; t < 9; ++t) {
        dorow(r0 - 4 + t, t, t >= 8);
    }
    // Main: full chunks of 9 rows (tc = 9,18,27 for SR=32); every row emits.
    // tc % 9 == 0 so the ring slot is exactly k (compile-time static).
#pragma unroll
    for (int tc = 9; tc + 9 <= SR + 8; tc += 9) {
#pragma unroll
        for (int k = 0; k < 9; ++k) {
            dorow(r0 - 4 + tc + k, k, true);
        }
    }
    // Tail: remaining SR+8-36 = 4 rows; 36 % 9 == 0 so slots are 0..3.
#pragma unroll
    for (int k = 0; k < SR + 8 - 36; ++k) {
        dorow(r0 - 4 + 36 + k, k, true);
    }
}

extern "C" void kernel_launch(void* const* d_in, const int* in_sizes, int n_in,
                              void* d_out, int out_size, void* d_ws, size_t ws_size,
                              hipStream_t stream) {
    const float* in = (const float*)d_in[0];
    float* out = (float*)d_out;
    dim3 grid(W / 256, H / (4 * SR));   // 32 x 64 blocks = 2048 = 8/CU
    dim3 block(64, 4, 1);               // 4 waves; wave ty handles strip 4*by+ty
    peak_stream<<<grid, block, 0, stream>>>(in, out);
}

// Round 3
// 451.047 us; speedup vs baseline: 1.3834x; 1.3834x over previous
//
#include <hip/hip_runtime.h>

// 9x9 local-max peak detection (threshold 0.5) on 8192x8192 fp32.
//
// Key identity: threshold t(x)=x*[x>0.5] commutes with max (monotone), so
//   conf[r][c] = (M > 0.5 && M == raw[r][c]) ? M : 0,  M = 9x9 raw max.
// 0-padding is equivalent to -inf padding: a pad value can only win the max
// when everything is <= 0, and then the >0.5 gate kills it anyway.
//
// Streaming structure (no LDS, no barriers):
//   wave = 256-col band (lane owns 4 cols via float4), rolls over SR output
//   rows. Per input row: 3 adjacent float4 loads (12 cols: col0-4..col0+7),
//   horizontal 9-max via shared-prefix, 9-deep register ring, vertical
//   9-max, predicate, coalesced NT float4 store. Unroll-by-9 keeps all ring
//   indices compile-time-static (registers, no spills).
//
// Round-3 change — undo the spill, keep the occupancy:
//   Round 2 paired SR=32 (grid 2048 = 8 blocks/CU = 32 waves/CU) with
//   __launch_bounds__(256,8). The bound capped VGPRs at 32 and the ring
//   state (~50 regs live) spilled to scratch: WRITE_SIZE 514 MB (~2x the
//   268 MB output), FETCH_SIZE 488 MB, VALUBusy 12.5%, dur 331 us. The
//   natural allocation is 44 VGPRs and 8 waves/SIMD already fit at 44
//   (8*44=352 <= 512; occupancy steps at 64) — the cap was never needed.
//   Keep SR=32; revert to __launch_bounds__(256,4). Expect WRITE back to
//   268 MB, VGPR=44, dur ~100-125 us.

#define W 8192
#define H 8192
#define THRESH 0.5f
#define SR 32   // output rows per wave-strip

typedef float v4f __attribute__((ext_vector_type(4)));

__device__ __forceinline__ v4f ld4(const float* __restrict__ in, int r, int c) {
    v4f v = {0.f, 0.f, 0.f, 0.f};
    if ((unsigned)c < (unsigned)W) {
        v = *(const v4f*)(in + (size_t)r * W + c);
    }
    return v;
}

__global__ __launch_bounds__(256, 4) void peak_stream(const float* __restrict__ in,
                                                      float* __restrict__ out) {
    const int lane = threadIdx.x;                       // 0..63
    const int col0 = blockIdx.x * 256 + lane * 4;       // this lane's 4 cols
    const int r0   = (blockIdx.y * 4 + threadIdx.y) * SR; // strip's first output row

    v4f hm[9];   // ring: horizontal 9-max of the last 9 input rows
    v4f ce[9];   // ring: raw center values (delayed 4 rows for the compare)

    // One input row: k = ring slot (compile-time const), rin = input row,
    // emit = produce output row rin-4 (center of the 9-row window).
    auto dorow = [&](int rin, int k, bool emit) {
        v4f l = {0.f, 0.f, 0.f, 0.f}, v = l, r = l;
        if ((unsigned)rin < (unsigned)H) {
            l = ld4(in, rin, col0 - 4);
            v = ld4(in, rin, col0);
            r = ld4(in, rin, col0 + 4);
        }
        // L = [l.x l.y l.z l.w v.x v.y v.z v.w r.x r.y r.z r.w]; out j = max L[j..j+8]
        const float common = fmaxf(fmaxf(fmaxf(l.w, v.x), fmaxf(v.y, v.z)),
                                   fmaxf(v.w, r.x));     // max L[3..8]
        const float m12  = fmaxf(l.y, l.z);
        const float m910 = fmaxf(r.y, r.z);
        v4f o;
        o.x = fmaxf(common, fmaxf(l.x, m12));
        o.y = fmaxf(common, fmaxf(m12, r.y));
        o.z = fmaxf(common, fmaxf(l.z, m910));
        o.w = fmaxf(common, fmaxf(m910, r.w));
        hm[k] = o;
        ce[k] = v;
        if (emit) {
            v4f m = hm[0];
#pragma unroll
            for (int j = 1; j < 9; ++j) {
                m.x = fmaxf(m.x, hm[j].x);
                m.y = fmaxf(m.y, hm[j].y);
                m.z = fmaxf(m.z, hm[j].z);
                m.w = fmaxf(m.w, hm[j].w);
            }
            const v4f c4 = ce[(k + 5) % 9];  // raw value at row rin-4
            v4f ov;
            ov.x = (m.x > THRESH && m.x == c4.x) ? m.x : 0.f;
            ov.y = (m.y > THRESH && m.y == c4.y) ? m.y : 0.f;
            ov.z = (m.z > THRESH && m.z == c4.z) ? m.z : 0.f;
            ov.w = (m.w > THRESH && m.w == c4.w) ? m.w : 0.f;
            const int rout = rin - 4;
            __builtin_nontemporal_store(ov, (v4f*)(out + (size_t)rout * W + col0));
        }
    };

    // Prologue: fill the ring (input rows r0-4 .. r0+4); slot 8 emits row r0.
#pragma unroll
    for (int t = 0; t < 9; ++t) {
        dorow(r0 - 4 + t, t, t >= 8);
    }
    // Main: full chunks of 9 rows (tc = 9,18,27 for SR=32); every row emits.
    // tc % 9 == 0 so the ring slot is exactly k (compile-time static).
#pragma unroll
    for (int tc = 9; tc + 9 <= SR + 8; tc += 9) {
#pragma unroll
        for (int k = 0; k < 9; ++k) {
            dorow(r0 - 4 + tc + k, k, true);
        }
    }
    // Tail: remaining SR+8-36 = 4 rows; 36 % 9 == 0 so slots are 0..3.
#pragma unroll
    for (int k = 0; k < SR + 8 - 36; ++k) {
        dorow(r0 - 4 + 36 + k, k, true);
    }
}

extern "C" void kernel_launch(void* const* d_in, const int* in_sizes, int n_in,
                              void* d_out, int out_size, void* d_ws, size_t ws_size,
                              hipStream_t stream) {
    const float* in = (const float*)d_in[0];
    float* out = (float*)d_out;
    dim3 grid(W / 256, H / (4 * SR));   // 32 x 64 blocks = 2048 = 8/CU
    dim3 block(64, 4, 1);               // 4 waves; wave ty handles strip 4*by+ty
    peak_stream<<<grid, block, 0, stream>>>(in, out);
}

// Round 4
// 451.005 us; speedup vs baseline: 1.3836x; 1.0001x over previous
//
#include <hip/hip_runtime.h>

// 9x9 local-max peak detection (threshold 0.5) on 8192x8192 fp32.
//
// Key identity: threshold t(x)=x*[x>0.5] commutes with max (monotone), so
//   conf[r][c] = (M > 0.5 && M == raw[r][c]) ? M : 0,  M = 9x9 raw max.
// 0-padding is equivalent to -inf padding: a pad value can only win the max
// when everything is <= 0, and then the >0.5 gate kills it anyway.
//
// Streaming structure (no LDS, no barriers):
//   wave = 256-col band (lane owns 4 cols via float4), rolls over SR output
//   rows. Per input row: 3 adjacent float4 loads, horizontal 9-max via
//   shared-prefix, 9-deep register ring, vertical 9-max, predicate,
//   coalesced NT float4 store. Unroll keeps ring indices static.
//
// Round-4 change — shrink ring state to buy pipeline depth:
//   Cross-round evidence: effective VGPR budget is ~256/SIMD; launch_bounds
//   (256,4) caps at 64 and R3's compiler ran exactly into it (VGPR=64),
//   leaving ~1 row of load prefetch -> latency-bound at 2.9 TB/s with every
//   pipe <45% (VALU 24%, occ 40%, traffic already 0.89x optimal).
//   The ce ring (raw center values, 36 VGPRs) is replaced by a 4-bit flag
//   ring (9 VGPRs):  M == raw_c  <=>  M == hmax_c && hmax_c == raw_c,
//   and (hmax_c == raw_c) is known at row time. -27 live regs => compiler
//   can hold 2-3 rows of loads in flight at unchanged occupancy.

#define W 8192
#define H 8192
#define THRESH 0.5f
#define SR 32   // output rows per wave-strip

typedef float v4f __attribute__((ext_vector_type(4)));

__device__ __forceinline__ v4f ld4(const float* __restrict__ in, int r, int c) {
    v4f v = {0.f, 0.f, 0.f, 0.f};
    if ((unsigned)c < (unsigned)W) {
        v = *(const v4f*)(in + (size_t)r * W + c);
    }
    return v;
}

__global__ __launch_bounds__(256, 4) void peak_stream(const float* __restrict__ in,
                                                      float* __restrict__ out) {
    const int lane = threadIdx.x;                       // 0..63
    const int col0 = blockIdx.x * 256 + lane * 4;       // this lane's 4 cols
    const int r0   = (blockIdx.y * 4 + threadIdx.y) * SR; // strip's first output row

    v4f hm[9];   // ring: horizontal 9-max of the last 9 input rows
    int fl[9];   // ring: 4-bit flags, bit j = (hmax.j == raw.j) for that row

    // One input row: k = ring slot (compile-time const), rin = input row,
    // emit = produce output row rin-4 (center of the 9-row window).
    auto dorow = [&](int rin, int k, bool emit) {
        v4f l = {0.f, 0.f, 0.f, 0.f}, v = l, r = l;
        if ((unsigned)rin < (unsigned)H) {
            l = ld4(in, rin, col0 - 4);
            v = ld4(in, rin, col0);
            r = ld4(in, rin, col0 + 4);
        }
        // L = [l.x l.y l.z l.w v.x v.y v.z v.w r.x r.y r.z r.w]; out j = max L[j..j+8]
        const float common = fmaxf(fmaxf(fmaxf(l.w, v.x), fmaxf(v.y, v.z)),
                                   fmaxf(v.w, r.x));     // max L[3..8]
        const float m12  = fmaxf(l.y, l.z);
        const float m910 = fmaxf(r.y, r.z);
        v4f o;
        o.x = fmaxf(common, fmaxf(l.x, m12));
        o.y = fmaxf(common, fmaxf(m12, r.y));
        o.z = fmaxf(common, fmaxf(l.z, m910));
        o.w = fmaxf(common, fmaxf(m910, r.w));
        hm[k] = o;
        fl[k] = (o.x == v.x ? 1 : 0) | (o.y == v.y ? 2 : 0) |
                (o.z == v.z ? 4 : 0) | (o.w == v.w ? 8 : 0);
        if (emit) {
            v4f m = hm[0];
#pragma unroll
            for (int j = 1; j < 9; ++j) {
                m.x = fmaxf(m.x, hm[j].x);
                m.y = fmaxf(m.y, hm[j].y);
                m.z = fmaxf(m.z, hm[j].z);
                m.w = fmaxf(m.w, hm[j].w);
            }
            const v4f hc = hm[(k + 5) % 9];  // h-max of the window-center row
            const int fc = fl[(k + 5) % 9];  // its (hmax==raw) flags
            v4f ov;
            ov.x = (m.x > THRESH && m.x == hc.x && (fc & 1)) ? m.x : 0.f;
            ov.y = (m.y > THRESH && m.y == hc.y && (fc & 2)) ? m.y : 0.f;
            ov.z = (m.z > THRESH && m.z == hc.z && (fc & 4)) ? m.z : 0.f;
            ov.w = (m.w > THRESH && m.w == hc.w && (fc & 8)) ? m.w : 0.f;
            const int rout = rin - 4;
            __builtin_nontemporal_store(ov, (v4f*)(out + (size_t)rout * W + col0));
        }
    };

    // Prologue: fill the ring (input rows r0-4 .. r0+4); slot 8 emits row r0.
#pragma unroll
    for (int t = 0; t < 9; ++t) {
        dorow(r0 - 4 + t, t, t >= 8);
    }
    // Main: full chunks of 9 rows (tc = 9,18,27 for SR=32); every row emits.
    // tc % 9 == 0 so the ring slot is exactly k (compile-time static).
#pragma unroll
    for (int tc = 9; tc + 9 <= SR + 8; tc += 9) {
#pragma unroll
        for (int k = 0; k < 9; ++k) {
            dorow(r0 - 4 + tc + k, k, true);
        }
    }
    // Tail: remaining SR+8-36 = 4 rows; 36 % 9 == 0 so slots are 0..3.
#pragma unroll
    for (int k = 0; k < SR + 8 - 36; ++k) {
        dorow(r0 - 4 + 36 + k, k, true);
    }
}

extern "C" void kernel_launch(void* const* d_in, const int* in_sizes, int n_in,
                              void* d_out, int out_size, void* d_ws, size_t ws_size,
                              hipStream_t stream) {
    const float* in = (const float*)d_in[0];
    float* out = (float*)d_out;
    dim3 grid(W / 256, H / (4 * SR));   // 32 x 64 blocks = 2048 = 8/CU
    dim3 block(64, 4, 1);               // 4 waves; wave ty handles strip 4*by+ty
    peak_stream<<<grid, block, 0, stream>>>(in, out);
}